// Round 8
// baseline (568.617 us; speedup 1.0000x reference)
//
#include <hip/hip_runtime.h>
#include <hip/hip_bf16.h>
#include <stdint.h>

typedef short short8 __attribute__((ext_vector_type(8)));
typedef float f32x4 __attribute__((ext_vector_type(4)));

#define NPB  100    // n-rows per block; 1000 blocks * 100 = 100000 exactly

__device__ __forceinline__ uint32_t f32_to_bf16_rne(float f) {
    uint32_t u = __builtin_bit_cast(uint32_t, f);
    uint32_t r = u + 0x7FFFu + ((u >> 16) & 1u);
    return r >> 16;
}
// packed f32x2 -> bf16x2 (RNE), single VALU op
__device__ __forceinline__ uint32_t cvt_pk_bf16(float lo, float hi) {
    uint32_t r;
    asm("v_cvt_pk_bf16_f32 %0, %1, %2" : "=v"(r) : "v"(lo), "v"(hi));
    return r;
}

// ---------------------------------------------------------------------------
// Pre-kernel: Wt[l][o][i] = bf16(w_l[i][o])  (transposed so A-fragments are
// contiguous-in-i 16B loads). 4 * 128 * 128 bf16 = 128 KB in d_ws.
// ---------------------------------------------------------------------------
__global__ void conv_weights(const float* __restrict__ w0, const float* __restrict__ w1,
                             const float* __restrict__ w2, const float* __restrict__ w3,
                             uint16_t* __restrict__ wt) {
    int idx = blockIdx.x * 256 + threadIdx.x;   // 0 .. 65535
    int l = idx >> 14;
    int o = (idx >> 7) & 127;
    int i = idx & 127;
    const float* w = (l == 0) ? w0 : (l == 1) ? w1 : (l == 2) ? w2 : w3;
    wt[idx] = (uint16_t)f32_to_bf16_rne(w[i * 128 + o]);
}

// ---------------------------------------------------------------------------
// Main kernel: NO LDS, NO BARRIERS. 1000 blocks x 512 thr (8 waves).
// A = weights (register-resident), B = x with c as the MFMA column dim ->
// direct coalesced global loads, 2-deep pipeline.
//   D[o][c] += w_l[i][o] * x[n][i][c]   (one n per MFMA group, K=128)
// Per-c degree l: 4 unmasked passes into acc[0..3], per-lane select at store.
// Fragments (16x16x32 bf16, m89-verified):
//   A: row=lane&15 (=o_local), k=(lane>>4)*8+j (=i)  -> wt[l][o][i] short8
//   B: col=lane&15 (=c),       k=(lane>>4)*8+j (=i)  -> x[n][i][c] dword loads
//   D: col=lane&15 (=c), row=(lane>>4)*4+reg (=o_local)
//
// ROUND 8 CHANGE: sched_barrier(0) fences between load-issue and compute
// regions. Round 6/7 post-mortem: the scheduler SANK all 32 loads to their
// uses (VGPR_Count=72 proves the pipeline state was never live), serializing
// each n behind a full load drain -> 3.2 TB/s duty-cycle ceiling. The fence
// makes sinking illegal; loads' dest regs stay live across compute and the
// waitcnt legalizer emits counted vmcnt(~32), keeping 8 KB/wave in flight
// at all times (64 KB/CU >> ~9 KB Little's-law need at 6.3 TB/s).
// Diagnostic: VGPR_Count must jump to ~170-210. If it stays ~72 -> theory
// dead, go inline-asm loads next.
// ---------------------------------------------------------------------------
__global__ void __launch_bounds__(512, 1)
isl_kernel(const float* __restrict__ x,
           const uint16_t* __restrict__ wt,
           float* __restrict__ out) {
    const int tid  = threadIdx.x;
    const int lane = tid & 63;
    const int wid  = tid >> 6;      // 0..7 = o-tile
    const int r16  = lane & 15;     // A-row (o_local) / B-col & D-col (c)
    const int kg   = lane >> 4;     // 0..3

    // ---- weight fragments, resident in registers for the whole block
    short8 wfr[4][4];               // [l][ks]
    {
        const uint16_t* wb = wt + (size_t)(wid * 16 + r16) * 128 + kg * 8;
        #pragma unroll
        for (int l = 0; l < 4; ++l)
            #pragma unroll
            for (int ks = 0; ks < 4; ++ks)
                wfr[l][ks] = *(const short8*)(wb + l * 16384 + ks * 32);
    }

    const int n0 = blockIdx.x * NPB;
    // per-lane x base: + kg*8 i's (=kg*128 floats) + c
    const float* xl = x + (size_t)n0 * 2048 + kg * 128 + r16;
    // per-lane out base: o = wid*16 + kg*4 (+reg), c = r16
    float* ob = out + (size_t)n0 * 2048 + (size_t)(wid * 16 + kg * 4) * 16 + r16;

    float vA[32], vB[32];

    // ---- issue loads for n0
    #pragma unroll
    for (int ks = 0; ks < 4; ++ks)
        #pragma unroll
        for (int j = 0; j < 8; ++j)
            vA[ks * 8 + j] = xl[(ks * 32 + j) * 16];

    __builtin_amdgcn_sched_barrier(0);

    #pragma unroll 1
    for (int nn = 0; nn < NPB; nn += 2) {
        // ---- issue loads for nn+1 (must stay here: fence below)
        {
            const float* p = xl + (size_t)(nn + 1) * 2048;
            #pragma unroll
            for (int ks = 0; ks < 4; ++ks)
                #pragma unroll
                for (int j = 0; j < 8; ++j)
                    vB[ks * 8 + j] = p[(ks * 32 + j) * 16];
        }
        __builtin_amdgcn_sched_barrier(0);
        // ---- compute + store nn (from vA); counted wait on vA only
        {
            short8 xb[4];
            #pragma unroll
            for (int ks = 0; ks < 4; ++ks) {
                uint32_t q0 = cvt_pk_bf16(vA[ks * 8 + 0], vA[ks * 8 + 1]);
                uint32_t q1 = cvt_pk_bf16(vA[ks * 8 + 2], vA[ks * 8 + 3]);
                uint32_t q2 = cvt_pk_bf16(vA[ks * 8 + 4], vA[ks * 8 + 5]);
                uint32_t q3 = cvt_pk_bf16(vA[ks * 8 + 6], vA[ks * 8 + 7]);
                uint32_t tmp[4] = {q0, q1, q2, q3};
                xb[ks] = *(const short8*)tmp;
            }
            f32x4 acc[4] = {{0,0,0,0},{0,0,0,0},{0,0,0,0},{0,0,0,0}};
            #pragma unroll
            for (int l = 0; l < 4; ++l)
                #pragma unroll
                for (int ks = 0; ks < 4; ++ks)
                    acc[l] = __builtin_amdgcn_mfma_f32_16x16x32_bf16(wfr[l][ks], xb[ks], acc[l], 0, 0, 0);
            float* po = ob + (size_t)nn * 2048;
            #pragma unroll
            for (int r = 0; r < 4; ++r) {
                float v = acc[0][r];
                v = (r16 >= 1) ? acc[1][r] : v;
                v = (r16 >= 4) ? acc[2][r] : v;
                v = (r16 >= 9) ? acc[3][r] : v;
                po[r * 16] = v;
            }
        }
        __builtin_amdgcn_sched_barrier(0);
        // ---- issue loads for nn+2 (into vA)
        if (nn + 2 < NPB) {
            const float* p = xl + (size_t)(nn + 2) * 2048;
            #pragma unroll
            for (int ks = 0; ks < 4; ++ks)
                #pragma unroll
                for (int j = 0; j < 8; ++j)
                    vA[ks * 8 + j] = p[(ks * 32 + j) * 16];
        }
        __builtin_amdgcn_sched_barrier(0);
        // ---- compute + store nn+1 (from vB); counted wait on vB only
        {
            short8 xb[4];
            #pragma unroll
            for (int ks = 0; ks < 4; ++ks) {
                uint32_t q0 = cvt_pk_bf16(vB[ks * 8 + 0], vB[ks * 8 + 1]);
                uint32_t q1 = cvt_pk_bf16(vB[ks * 8 + 2], vB[ks * 8 + 3]);
                uint32_t q2 = cvt_pk_bf16(vB[ks * 8 + 4], vB[ks * 8 + 5]);
                uint32_t q3 = cvt_pk_bf16(vB[ks * 8 + 6], vB[ks * 8 + 7]);
                uint32_t tmp[4] = {q0, q1, q2, q3};
                xb[ks] = *(const short8*)tmp;
            }
            f32x4 acc[4] = {{0,0,0,0},{0,0,0,0},{0,0,0,0},{0,0,0,0}};
            #pragma unroll
            for (int l = 0; l < 4; ++l)
                #pragma unroll
                for (int ks = 0; ks < 4; ++ks)
                    acc[l] = __builtin_amdgcn_mfma_f32_16x16x32_bf16(wfr[l][ks], xb[ks], acc[l], 0, 0, 0);
            float* po = ob + (size_t)(nn + 1) * 2048;
            #pragma unroll
            for (int r = 0; r < 4; ++r) {
                float v = acc[0][r];
                v = (r16 >= 1) ? acc[1][r] : v;
                v = (r16 >= 4) ? acc[2][r] : v;
                v = (r16 >= 9) ? acc[3][r] : v;
                po[r * 16] = v;
            }
        }
        __builtin_amdgcn_sched_barrier(0);
    }
}

extern "C" void kernel_launch(void* const* d_in, const int* in_sizes, int n_in,
                              void* d_out, int out_size, void* d_ws, size_t ws_size,
                              hipStream_t stream) {
    const float* x  = (const float*)d_in[0];
    const float* w0 = (const float*)d_in[1];
    const float* w1 = (const float*)d_in[2];
    const float* w2 = (const float*)d_in[3];
    const float* w3 = (const float*)d_in[4];
    uint16_t* wt = (uint16_t*)d_ws;          // 128 KB scratch
    float* out = (float*)d_out;

    conv_weights<<<256, 256, 0, stream>>>(w0, w1, w2, w3, wt);
    isl_kernel<<<1000, 512, 0, stream>>>(x, wt, out);
}

// Round 9
// 344.799 us; speedup vs baseline: 1.6491x; 1.6491x over previous
//
#include <hip/hip_runtime.h>
#include <stdint.h>

typedef short short8 __attribute__((ext_vector_type(8)));
typedef float f32x4 __attribute__((ext_vector_type(4)));

#define NPB     100    // n-rows per block; 1000 blocks * 100 = 100000 exactly
#define NBLOCKS 1000

__device__ __forceinline__ uint32_t f32_to_bf16_rne(float f) {
    uint32_t u = __builtin_bit_cast(uint32_t, f);
    uint32_t r = u + 0x7FFFu + ((u >> 16) & 1u);
    return r >> 16;
}
// packed f32x2 -> bf16x2 (RNE), single VALU op
__device__ __forceinline__ uint32_t cvt_pk_bf16(float lo, float hi) {
    uint32_t r;
    asm("v_cvt_pk_bf16_f32 %0, %1, %2" : "=v"(r) : "v"(lo), "v"(hi));
    return r;
}

// async global->LDS, 16B per lane; LDS dest = wave-uniform base + lane*16
#define GLOAD_LDS16(g, l)                                                  \
    __builtin_amdgcn_global_load_lds(                                      \
        (const __attribute__((address_space(1))) void*)(g),                \
        (__attribute__((address_space(3))) void*)(l), 16, 0, 0)

// ---------------------------------------------------------------------------
// Pre-kernel: Wt[l][o][i] = bf16(w_l[i][o])  (transposed so A-fragments are
// contiguous-in-i 16B loads). 4 * 128 * 128 bf16 = 128 KB in d_ws.
// ---------------------------------------------------------------------------
__global__ void conv_weights(const float* __restrict__ w0, const float* __restrict__ w1,
                             const float* __restrict__ w2, const float* __restrict__ w3,
                             uint16_t* __restrict__ wt) {
    int idx = blockIdx.x * 256 + threadIdx.x;   // 0 .. 65535
    int l = idx >> 14;
    int o = (idx >> 7) & 127;
    int i = idx & 127;
    const float* w = (l == 0) ? w0 : (l == 1) ? w1 : (l == 2) ? w2 : w3;
    wt[idx] = (uint16_t)f32_to_bf16_rne(w[i * 128 + o]);
}

// ---------------------------------------------------------------------------
// Main kernel: async-DMA pipelined, 1000 blocks x 512 thr (8 waves).
// r6-8 post-mortem: VGPR-staged prefetch is unwinnable (regalloc collapses the
// pipeline: VGPR stuck at 72-80 across 3 attempts), and per-lane scalar loads
// are L1-request-bound (8 waves re-read the same row: ~1024 lines/row vs
// 800cy HBM budget). Fix: global_load_lds (no dest VGPRs -> nothing for
// regalloc to collapse; waits are OUR counted vmcnt), x crosses TA once.
//
// Structure: 4-buffer LDS ring of 8 KB f32 rows. Per row each of 512 threads
// issues ONE global_load_lds dwordx4 (8 KB/row), 3 rows prefetch-ahead.
// Loop r: [s_waitcnt vmcnt(14); s_barrier] -> issue load(r+3) -> compute(r).
//   vmcnt(14): ops issued after load(r) = stores(r-3)x4 + load(r+1) +
//   stores(r-2)x4 + load(r+2) + stores(r-1)x4 = 14 (in-order retirement).
//   Prologue drains vmcnt(0) once so the count is loop-invariant; tail
//   (r > NPB-3) uses vmcnt(2). vmcnt NEVER drained to 0 in steady state.
// Buffer safety: load(r+3) -> buf[(r+3)&3] = buf[(r-1)&3]; issued after
// barrier(r), by which all waves finished compute(r-1). &3 of {r..r+3} distinct.
//
// Compute (per wave, o-tile = wid): A = wfr (register-resident weights),
// B = x from LDS: lane(c=r16, kg) reads f32 x[i=ks*32+kg*8+j][c], cvt_pk to
// bf16x8. 4 passes over l into acc[0..3], per-lane select at store (c fixed
// per lane). MFMA 16x16x32 bf16 (m89-verified layout).
// Per-CU budget: HBM 1600cy/row (binding), LDS ~850 (4-way read conflicts),
// MFMA ~153, TA ~256 -> expect ~260-290us total.
// ---------------------------------------------------------------------------
__global__ void __launch_bounds__(512, 1)
isl_kernel(const float* __restrict__ x,
           const uint16_t* __restrict__ wt,
           float* __restrict__ out) {
    __shared__ uint8_t ldsbuf[4][8192];
    const int tid  = threadIdx.x;
    const int lane = tid & 63;
    const int wid  = tid >> 6;      // 0..7 = o-tile
    const int r16  = lane & 15;     // A-row (o_local) / B-col & D-col (c)
    const int kg   = lane >> 4;     // 0..3

    // ---- weight fragments, register-resident for the whole block
    short8 wfr[4][4];               // [l][ks]
    {
        const uint16_t* wb = wt + (size_t)(wid * 16 + r16) * 128 + kg * 8;
        #pragma unroll
        for (int l = 0; l < 4; ++l)
            #pragma unroll
            for (int ks = 0; ks < 4; ++ks)
                wfr[l][ks] = *(const short8*)(wb + l * 16384 + ks * 32);
    }

    const int n0 = blockIdx.x * NPB;
    // per-thread global src: thread tid covers bytes [tid*16, tid*16+16) of a row
    const uint8_t* xg = (const uint8_t*)(x + (size_t)n0 * 2048) + (size_t)tid * 16;

    // ---- prologue: stage rows 0..2, drain once, sync
    #pragma unroll
    for (int r = 0; r < 3; ++r)
        GLOAD_LDS16(xg + (size_t)r * 8192, &ldsbuf[r][wid * 1024]);
    asm volatile("s_waitcnt vmcnt(0)" ::: "memory");
    __builtin_amdgcn_s_barrier();

    float* po_base = out + (size_t)n0 * 2048 + (size_t)(wid * 16 + kg * 4) * 16 + r16;

    #pragma unroll 1
    for (int r = 0; r < NPB; ++r) {
        if (r > 0) {
            if (r <= NPB - 3)
                asm volatile("s_waitcnt vmcnt(14)" ::: "memory");
            else
                asm volatile("s_waitcnt vmcnt(2)" ::: "memory");
            __builtin_amdgcn_s_barrier();
        }
        // ---- issue prefetch for row r+3 (ring slot (r+3)&3 == (r-1)&3, now free)
        if (r + 3 < NPB)
            GLOAD_LDS16(xg + (size_t)(r + 3) * 8192, &ldsbuf[(r + 3) & 3][wid * 1024]);

        // ---- compute row r from LDS ring slot r&3
        const float* rowp = (const float*)&ldsbuf[r & 3][0];
        short8 xb[4];
        #pragma unroll
        for (int ks = 0; ks < 4; ++ks) {
            float f[8];
            #pragma unroll
            for (int j = 0; j < 8; ++j)
                f[j] = rowp[(ks * 32 + kg * 8 + j) * 16 + r16];
            uint32_t q[4];
            #pragma unroll
            for (int h = 0; h < 4; ++h)
                q[h] = cvt_pk_bf16(f[2 * h], f[2 * h + 1]);
            xb[ks] = *(const short8*)q;
        }
        f32x4 acc[4] = {{0,0,0,0},{0,0,0,0},{0,0,0,0},{0,0,0,0}};
        #pragma unroll
        for (int l = 0; l < 4; ++l)
            #pragma unroll
            for (int ks = 0; ks < 4; ++ks)
                acc[l] = __builtin_amdgcn_mfma_f32_16x16x32_bf16(wfr[l][ks], xb[ks], acc[l], 0, 0, 0);

        // ---- store: 4 dwords (o = wid*16 + kg*4 + rr, c = r16), per-lane l-select
        float* po = po_base + (size_t)r * 2048;
        #pragma unroll
        for (int rr = 0; rr < 4; ++rr) {
            float v = acc[0][rr];
            v = (r16 >= 1) ? acc[1][rr] : v;
            v = (r16 >= 4) ? acc[2][rr] : v;
            v = (r16 >= 9) ? acc[3][rr] : v;
            po[rr * 16] = v;
        }
    }
}

extern "C" void kernel_launch(void* const* d_in, const int* in_sizes, int n_in,
                              void* d_out, int out_size, void* d_ws, size_t ws_size,
                              hipStream_t stream) {
    const float* x  = (const float*)d_in[0];
    const float* w0 = (const float*)d_in[1];
    const float* w1 = (const float*)d_in[2];
    const float* w2 = (const float*)d_in[3];
    const float* w3 = (const float*)d_in[4];
    uint16_t* wt = (uint16_t*)d_ws;          // 128 KB scratch
    float* out = (float*)d_out;

    conv_weights<<<256, 256, 0, stream>>>(w0, w1, w2, w3, wt);
    isl_kernel<<<NBLOCKS, 512, 0, stream>>>(x, wt, out);
}

// Round 11
// 342.838 us; speedup vs baseline: 1.6586x; 1.0057x over previous
//
#include <hip/hip_runtime.h>
#include <stdint.h>

typedef short short8 __attribute__((ext_vector_type(8)));
typedef float f32x4 __attribute__((ext_vector_type(4)));

#define NPB     100    // n-rows per block; 1000 blocks * 100 = 100000 exactly
#define NBLOCKS 1000

__device__ __forceinline__ uint32_t f32_to_bf16_rne(float f) {
    uint32_t u = __builtin_bit_cast(uint32_t, f);
    uint32_t r = u + 0x7FFFu + ((u >> 16) & 1u);
    return r >> 16;
}
// packed f32x2 -> bf16x2 (RNE), single VALU op
__device__ __forceinline__ uint32_t cvt_pk_bf16(float lo, float hi) {
    uint32_t r;
    asm("v_cvt_pk_bf16_f32 %0, %1, %2" : "=v"(r) : "v"(lo), "v"(hi));
    return r;
}

// async global->LDS, 16B per lane; LDS dest = wave-uniform base + lane*16
#define GLOAD_LDS16(g, l)                                                  \
    __builtin_amdgcn_global_load_lds(                                      \
        (const __attribute__((address_space(1))) void*)(g),                \
        (__attribute__((address_space(3))) void*)(l), 16, 0, 0)

// ---------------------------------------------------------------------------
// Pre-kernel: Wt[l][o][i] = bf16(w_l[i][o])  (transposed so A-fragments are
// contiguous-in-i 16B loads). 4 * 128 * 128 bf16 = 128 KB in d_ws.
// ---------------------------------------------------------------------------
__global__ void conv_weights(const float* __restrict__ w0, const float* __restrict__ w1,
                             const float* __restrict__ w2, const float* __restrict__ w3,
                             uint16_t* __restrict__ wt) {
    int idx = blockIdx.x * 256 + threadIdx.x;   // 0 .. 65535
    int l = idx >> 14;
    int o = (idx >> 7) & 127;
    int i = idx & 127;
    const float* w = (l == 0) ? w0 : (l == 1) ? w1 : (l == 2) ? w2 : w3;
    wt[idx] = (uint16_t)f32_to_bf16_rne(w[i * 128 + o]);
}

// ---------------------------------------------------------------------------
// Main kernel: async-DMA pipelined, 1000 blocks x 512 thr (8 waves).
// Round 9 structure (344 us) + granule swizzle killing the 4-way LDS read
// bank conflict (r9 audit: LDS reads 2350 cy/row > HBM 1560 cy/row).
//
// Swizzle (rule #21, both-sides): LDS layout idx(i,c) = (i ^ ((i>>3)&1))*16+c,
// realized by pre-swizzled global source granule srcg = tid ^ (((tid>>5)&1)<<2)
// (involution, 16B granules, same 64B lines -> coalescing preserved).
// Read side: rowp[((i) ^ (kg&1))*16 + c] returns x[i][c] DIRECTLY in
// ascending-i order (location i^kx1 holds x[(i^kx1)^b] = x[i], b(i^kx1)=kx1
// since bit-0 XOR preserves bit 3). ROUND 11 FIX: r10 additionally swapped
// the cvt_pk pair for kg-odd lanes — a double-correction that paired x
// values with wrong k in the dot product (absmax 78.75). Pack is now
// unconditional f-order.
// Bank check: banks 16*((j&1)^(kg&1)) + c -> 32 banks x 2 lanes = free (m136).
//
// Ring/wait structure unchanged: 4-buffer ring of 8 KB rows, 3 ahead,
// vmcnt(14) counted steady-state (never 0), barrier per row.
// Compute: A = wfr (register-resident), B = x from LDS (cvt_pk to bf16),
// 4 unmasked l-passes into acc[0..3], per-lane select at store.
// MFMA 16x16x32 bf16 (m89-verified layout).
// ---------------------------------------------------------------------------
__global__ void __launch_bounds__(512, 1)
isl_kernel(const float* __restrict__ x,
           const uint16_t* __restrict__ wt,
           float* __restrict__ out) {
    __shared__ uint8_t ldsbuf[4][8192];
    const int tid  = threadIdx.x;
    const int lane = tid & 63;
    const int wid  = tid >> 6;      // 0..7 = o-tile
    const int r16  = lane & 15;     // A-row (o_local) / B-col & D-col (c)
    const int kg   = lane >> 4;     // 0..3
    const int kx1  = kg & 1;        // read-side swizzle bit

    // ---- weight fragments, register-resident for the whole block
    short8 wfr[4][4];               // [l][ks]
    {
        const uint16_t* wb = wt + (size_t)(wid * 16 + r16) * 128 + kg * 8;
        #pragma unroll
        for (int l = 0; l < 4; ++l)
            #pragma unroll
            for (int ks = 0; ks < 4; ++ks)
                wfr[l][ks] = *(const short8*)(wb + l * 16384 + ks * 32);
    }

    const int n0 = blockIdx.x * NPB;
    // per-thread global src granule, pre-swizzled (involution g ^ ((g>>5&1)<<2))
    const int srcg = tid ^ (((tid >> 5) & 1) << 2);
    const uint8_t* xg = (const uint8_t*)(x + (size_t)n0 * 2048) + (size_t)srcg * 16;

    // ---- prologue: stage rows 0..2, drain once, sync
    #pragma unroll
    for (int r = 0; r < 3; ++r)
        GLOAD_LDS16(xg + (size_t)r * 8192, &ldsbuf[r][wid * 1024]);
    asm volatile("s_waitcnt vmcnt(0)" ::: "memory");
    __builtin_amdgcn_s_barrier();

    float* po_base = out + (size_t)n0 * 2048 + (size_t)(wid * 16 + kg * 4) * 16 + r16;

    #pragma unroll 1
    for (int r = 0; r < NPB; ++r) {
        if (r > 0) {
            if (r <= NPB - 3)
                asm volatile("s_waitcnt vmcnt(14)" ::: "memory");
            else
                asm volatile("s_waitcnt vmcnt(2)" ::: "memory");
            __builtin_amdgcn_s_barrier();
        }
        // ---- issue prefetch for row r+3 (ring slot (r+3)&3 == (r-1)&3, now free)
        if (r + 3 < NPB)
            GLOAD_LDS16(xg + (size_t)(r + 3) * 8192, &ldsbuf[(r + 3) & 3][wid * 1024]);

        // ---- compute row r from LDS ring slot r&3 (swizzled read: i ^= kg&1)
        const float* rowp = (const float*)&ldsbuf[r & 3][0];
        short8 xb[4];
        #pragma unroll
        for (int ks = 0; ks < 4; ++ks) {
            float f[8];
            #pragma unroll
            for (int j = 0; j < 8; ++j)
                f[j] = rowp[((ks * 32 + kg * 8 + j) ^ kx1) * 16 + r16];
            uint32_t q[4];
            // f[j] is already x[i=ks*32+kg*8+j][c] in ascending-i order:
            // pack unconditionally (r10's conditional swap was the bug).
            #pragma unroll
            for (int h = 0; h < 4; ++h)
                q[h] = cvt_pk_bf16(f[2 * h], f[2 * h + 1]);
            xb[ks] = *(const short8*)q;
        }
        f32x4 acc[4] = {{0,0,0,0},{0,0,0,0},{0,0,0,0},{0,0,0,0}};
        #pragma unroll
        for (int l = 0; l < 4; ++l)
            #pragma unroll
            for (int ks = 0; ks < 4; ++ks)
                acc[l] = __builtin_amdgcn_mfma_f32_16x16x32_bf16(wfr[l][ks], xb[ks], acc[l], 0, 0, 0);

        // ---- store: 4 dwords (o = wid*16 + kg*4 + rr, c = r16), per-lane l-select
        float* po = po_base + (size_t)r * 2048;
        #pragma unroll
        for (int rr = 0; rr < 4; ++rr) {
            float v = acc[0][rr];
            v = (r16 >= 1) ? acc[1][rr] : v;
            v = (r16 >= 4) ? acc[2][rr] : v;
            v = (r16 >= 9) ? acc[3][rr] : v;
            po[rr * 16] = v;
        }
    }
}

extern "C" void kernel_launch(void* const* d_in, const int* in_sizes, int n_in,
                              void* d_out, int out_size, void* d_ws, size_t ws_size,
                              hipStream_t stream) {
    const float* x  = (const float*)d_in[0];
    const float* w0 = (const float*)d_in[1];
    const float* w1 = (const float*)d_in[2];
    const float* w2 = (const float*)d_in[3];
    const float* w3 = (const float*)d_in[4];
    uint16_t* wt = (uint16_t*)d_ws;          // 128 KB scratch
    float* out = (float*)d_out;

    conv_weights<<<256, 256, 0, stream>>>(w0, w1, w2, w3, wt);
    isl_kernel<<<NBLOCKS, 512, 0, stream>>>(x, wt, out);
}